// Round 9
// baseline (301.608 us; speedup 1.0000x reference)
//
#include <hip/hip_runtime.h>
#include <hip/hip_bf16.h>

// PSWarpHead round 15. r14 structure with the A-dbuf PARITY BUG fixed.
//   r14 post-mortem: absmax 0.14 = A/B k-step mispairing. s0=2S is always
//   even -> buf(s0) is ALWAYS aq[0]; r14's c0=S&1 made odd-S iterations
//   compute A(k+1)*B(k) with undrained registers. Fix: c0=0,c1=1 constant.
//   Structure (unchanged from r14): 6-wave row blocks (800); B staged once
//   per block into a 6-slot LDS ring (global_load_lds pair-staging, 3 loads
//   per wave per pair), consumed via ds_read_b128 on the idle LDS pipe; raw
//   s_barrier once per 2 steps; counted vmcnt keeps the r12 A-register
//   pipeline in flight. Theory: conv1 was vector-load-path bound (18KB/wave/
//   step); sharing B across 6 waves halves that.
//   transpose (r13) / prep / sample unchanged.

#define WDIM 176
#define HDIM 200
#define HWDIM 35200
#define CIN 256
#define PDIM 28
#define NBOX 2048

typedef __attribute__((ext_vector_type(8))) short bf16x8;
typedef __attribute__((ext_vector_type(4))) float floatx4;
typedef __attribute__((ext_vector_type(16))) float floatx16;

__device__ __forceinline__ unsigned short f2bf(float f) {
    unsigned int u; __builtin_memcpy(&u, &f, 4);
    unsigned int r = u + 0x7FFFu + ((u >> 16) & 1u);   // RNE
    return (unsigned short)(r >> 16);
}

__device__ __forceinline__ void async_copy16(const void* g, void* l) {
    __builtin_amdgcn_global_load_lds(
        (const __attribute__((address_space(1))) void*)g,
        (__attribute__((address_space(3))) void*)l, 16, 0, 0);
}

// ---------- transpose: fp32 x [b][c][hw] -> bf16 xT2 [b][ksub][hw][16c] ----------
__global__ __launch_bounds__(256) void transpose_kernel(const float* __restrict__ x,
                                                        unsigned short* __restrict__ xT2) {
    __shared__ unsigned short st[64][72];
    int b = blockIdx.z, c0 = blockIdx.y * 64, px0 = blockIdx.x * 64;
    int t = threadIdx.x;

    int c_l = t >> 2, pq = t & 3;
    const float* sp = x + (long)(b * CIN + c0 + c_l) * HWDIM + px0 + pq * 16;
    float4 v0 = ((const float4*)sp)[0], v1 = ((const float4*)sp)[1];
    float4 v2 = ((const float4*)sp)[2], v3 = ((const float4*)sp)[3];
    int pr = pq * 16;
    st[pr +  0][c_l] = f2bf(v0.x); st[pr +  1][c_l] = f2bf(v0.y);
    st[pr +  2][c_l] = f2bf(v0.z); st[pr +  3][c_l] = f2bf(v0.w);
    st[pr +  4][c_l] = f2bf(v1.x); st[pr +  5][c_l] = f2bf(v1.y);
    st[pr +  6][c_l] = f2bf(v1.z); st[pr +  7][c_l] = f2bf(v1.w);
    st[pr +  8][c_l] = f2bf(v2.x); st[pr +  9][c_l] = f2bf(v2.y);
    st[pr + 10][c_l] = f2bf(v2.z); st[pr + 11][c_l] = f2bf(v2.w);
    st[pr + 12][c_l] = f2bf(v3.x); st[pr + 13][c_l] = f2bf(v3.y);
    st[pr + 14][c_l] = f2bf(v3.z); st[pr + 15][c_l] = f2bf(v3.w);
    __syncthreads();

    int w = t >> 6, l = t & 63;
    int ks = (c0 >> 4) + w;
    long pbase = ((long)(b * 16 + ks) * HWDIM + px0) * 16;
#pragma unroll
    for (int i = 0; i < 2; i++) {
        int px_l = i * 32 + (l >> 1);
        int hc = l & 1;
        bf16x8 frag = *(const bf16x8*)&st[px_l][w * 16 + hc * 8];
        *(bf16x8*)(xT2 + pbase + px_l * 16 + hc * 8) = frag;
    }
}

// ---------- prep: BwT2[f=tap*16+ks][lane=kh*32+n][8c] bf16; BN fold ----------
__global__ void prep_kernel(const float* __restrict__ w1,
                            const float* __restrict__ g, const float* __restrict__ bt,
                            const float* __restrict__ mn, const float* __restrict__ vr,
                            unsigned short* __restrict__ BwT2,
                            float* __restrict__ scale, float* __restrict__ shift) {
    int idx = blockIdx.x * 256 + threadIdx.x;
    if (idx < 9 * 16 * 64 * 8) {               // 73728
        int f = idx >> 9;
        int tap = f >> 4, ks = f & 15;
        int l = (idx >> 3) & 63;
        int e = idx & 7;
        int n = l & 31, kh = l >> 5;
        int c = ks * 16 + kh * 8 + e;
        BwT2[idx] = (n < PDIM) ? f2bf(w1[n * 2304 + c * 9 + tap]) : (unsigned short)0;
    } else if (idx < 73728 + 32) {
        int p = idx - 73728;
        if (p < PDIM) {
            float inv = g[p] / sqrtf(vr[p] + 1e-3f);
            scale[p] = inv;
            shift[p] = bt[p] - mn[p] * inv;
        } else { scale[p] = 0.f; shift[p] = 0.f; }
    }
}

// ---------- conv1: 6-wave blocks; B via LDS ring; A register pipeline ----------
// block = (b, y): wave w -> px [32w, 32w+32) (w=5: 16 valid). 16 k-steps.
__global__ __launch_bounds__(384) void conv1_kernel(const unsigned short* __restrict__ xT2,
                                                    const unsigned short* __restrict__ BwT2,
                                                    const float* __restrict__ scale,
                                                    const float* __restrict__ shift,
                                                    const float* __restrict__ w2,
                                                    float* __restrict__ feat2) {
    // B ring: 6 step-slots x 9 frags x 1KB = 55,296 B. Epilogue t2 tiles
    // (6 waves x 4608 B = 27,648 B) alias the ring after the final barrier.
    __shared__ unsigned short Bs[6 * 9 * 512];

    // XCD-chunked bijective swizzle over 800 blocks (800 % 8 == 0)
    int wg = blockIdx.y * 200 + blockIdx.x;
    int nl = (wg & 7) * 100 + (wg >> 3);
    int b = nl / 200, y = nl % 200;

    int lane = threadIdx.x & 63, w = threadIdx.x >> 6;   // w in 0..5
    int r32 = lane & 31, khalf = lane >> 5;
    int lane16 = lane * 16;
    int pxbase = w * 32;

    bool rowok[3];
#pragma unroll
    for (int rr = 0; rr < 3; rr++) rowok[rr] = (y + rr - 1 >= 0) && (y + rr - 1 < HDIM);
    bool edge = (w == 0) || (w == 5);

    bool xval[3];
    int  voff[3];
#pragma unroll
    for (int d = 0; d < 3; d++) {
        int xp = pxbase + r32 + d - 1;
        xval[d] = (xp >= 0) && (xp < WDIM);
        int xc = xp < 0 ? 0 : (xp > WDIM - 1 ? WDIM - 1 : xp);
        voff[d] = xc * 32 + khalf * 16;
    }

    const char* abase[3];
#pragma unroll
    for (int rr = 0; rr < 3; rr++) {
        int yc = y + rr - 1;
        yc = yc < 0 ? 0 : (yc > HDIM - 1 ? HDIM - 1 : yc);
        abase[rr] = (const char*)xT2 + ((long)b * 16 * HWDIM + (long)yc * WDIM) * 32;
    }
    const long KS = (long)HWDIM * 32;
    const char* bwb = (const char*)BwT2;

    // stage frags F=3w..3w+2 of the pair starting at step s2 (3 loads)
#define STAGE_PAIR(s2) {                                                      \
        _Pragma("unroll")                                                     \
        for (int k = 0; k < 3; k++) {                                         \
            int F = 3 * w + k;                                                \
            int stp = (s2) + (F >= 9 ? 1 : 0);                                \
            int tap = F >= 9 ? F - 9 : F;                                     \
            async_copy16(bwb + tap * 16384 + stp * 1024 + lane16,             \
                         (char*)Bs + (stp % 6) * 9216 + tap * 1024);          \
        }                                                                     \
    }

    // prologue: stage pairs 0,1 (B0..B3), issue A(0); publish
    STAGE_PAIR(0)
    STAGE_PAIR(2)
    bf16x8 aq[2][9];
#pragma unroll
    for (int t = 0; t < 9; t++)
        aq[0][t] = *(const bf16x8*)(abase[t / 3] + voff[t % 3]);
    __builtin_amdgcn_sched_barrier(0);
    asm volatile("s_waitcnt vmcnt(9)" ::: "memory");   // 6 stage loads done
    __builtin_amdgcn_sched_barrier(0);
    asm volatile("s_barrier" ::: "memory");            // B0..B3 visible

    floatx16 acc = {};

#define DO_MFMA(AQ)                                                           \
        if (!edge) {                                                          \
            _Pragma("unroll")                                                 \
            for (int t = 0; t < 9; t++) {                                     \
                if (!rowok[t / 3]) continue;                                  \
                acc = __builtin_amdgcn_mfma_f32_32x32x16_bf16(AQ[t], bq[t], acc, 0, 0, 0); \
            }                                                                 \
        } else {                                                              \
            _Pragma("unroll")                                                 \
            for (int t = 0; t < 9; t++) {                                     \
                if (!rowok[t / 3]) continue;                                  \
                bf16x8 af = AQ[t];                                            \
                if (!xval[t % 3]) af = (bf16x8)0;                             \
                acc = __builtin_amdgcn_mfma_f32_32x32x16_bf16(af, bq[t], acc, 0, 0, 0); \
            }                                                                 \
        }

#pragma unroll
    for (int S = 0; S < 8; S++) {
        const int s0 = 2 * S, s1 = 2 * S + 1;
        // PARITY FIX (r14 bug): s0=2S is always even -> A(s0) lives in aq[0]
        // ALWAYS; A(s1) in aq[1]. r14's c0=S&1 mispaired A(k+1) with B(k) on
        // odd S and read undrained registers.
        // ---- even step s0: compute aq[0], load aq[1] <- A(s1) ----
        {
            if (S <= 5) STAGE_PAIR(2 * S + 4)                   // 3 stage loads
#pragma unroll
            for (int t = 0; t < 9; t++)                          // A(s1): 9 loads
                aq[1][t] = *(const bf16x8*)(abase[t / 3] + KS * s1 + voff[t % 3]);
            bf16x8 bq[9];
#pragma unroll
            for (int t = 0; t < 9; t++)
                bq[t] = *(const bf16x8*)((const char*)Bs + (s0 % 6) * 9216 + t * 1024 + lane16);
            __builtin_amdgcn_sched_barrier(0);
            if (S <= 5) { asm volatile("s_waitcnt vmcnt(12)" ::: "memory"); }
            else        { asm volatile("s_waitcnt vmcnt(9)"  ::: "memory"); }
            __builtin_amdgcn_sched_barrier(0);
            DO_MFMA(aq[0])
        }
        // ---- odd step s1: compute aq[1], load aq[0] <- A(s1+1) ----
        {
            if (S <= 6) {
#pragma unroll
                for (int t = 0; t < 9; t++)                      // A(s1+1): 9 loads
                    aq[0][t] = *(const bf16x8*)(abase[t / 3] + KS * (s1 + 1) + voff[t % 3]);
            }
            bf16x8 bq[9];
#pragma unroll
            for (int t = 0; t < 9; t++)
                bq[t] = *(const bf16x8*)((const char*)Bs + (s1 % 6) * 9216 + t * 1024 + lane16);
            __builtin_amdgcn_sched_barrier(0);
            if (S <= 6) { asm volatile("s_waitcnt vmcnt(9)" ::: "memory"); }
            else        { asm volatile("s_waitcnt vmcnt(0)" ::: "memory"); }
            __builtin_amdgcn_sched_barrier(0);
            DO_MFMA(aq[1])
            if (S <= 5) { asm volatile("s_barrier" ::: "memory"); }  // publish pair S+2
        }
    }
#undef DO_MFMA
#undef STAGE_PAIR

    __syncthreads();                            // ring dead; safe to alias t2

    // ---- epilogue: BN + relu -> per-wave LDS tile -> fp32 conv2 matvec ----
    float* t2f = (float*)Bs + w * (32 * 36);    // 4608 B per wave
    {
        float sc = scale[r32], sh2 = shift[r32];
#pragma unroll
        for (int i = 0; i < 16; i++) {
            int prow = (i & 3) + 8 * (i >> 2) + 4 * khalf;
            float v = fmaf(acc[i], sc, sh2);
            t2f[prow * 36 + r32] = v > 0.f ? v : 0.f;
        }
    }
    long rowpix = (long)b * HWDIM + (long)y * WDIM;
    int n_l = r32;
    float4 w2r[7];
#pragma unroll
    for (int jj = 0; jj < 7; jj++) {
        if (n_l < PDIM) w2r[jj] = ((const float4*)(w2 + n_l * PDIM))[jj];
        else            w2r[jj] = make_float4(0.f, 0.f, 0.f, 0.f);
    }
#pragma unroll
    for (int i = 0; i < 16; i++) {
        int pxl = khalf * 16 + i;
        float s = 0.f;
#pragma unroll
        for (int jj = 0; jj < 7; jj++) {
            float4 a = *(const float4*)&t2f[pxl * 36 + jj * 4];
            s = fmaf(a.x, w2r[jj].x, s); s = fmaf(a.y, w2r[jj].y, s);
            s = fmaf(a.z, w2r[jj].z, s); s = fmaf(a.w, w2r[jj].w, s);
        }
        int px = pxbase + pxl;
        if (n_l < PDIM && px < WDIM) feat2[(rowpix + px) * PDIM + n_l] = s;
    }
}

// ---------- PS bilinear sampler on precomputed conv2 output (scalar gather) ----------
__global__ __launch_bounds__(256) void sample_kernel(const float* __restrict__ boxes,
                                                     const float* __restrict__ feat2,
                                                     float* __restrict__ out) {
    int gid = blockIdx.x * 256 + threadIdx.x;
    int box = gid >> 5;              // 32 lanes per box
    int pl = gid & 31;
    int b = box >> 11;
    float val = 0.f;
    if (pl < PDIM) {
        long bb = (long)box * 7;
        float xg = boxes[bb + 0], yg = boxes[bb + 1];
        float wg = boxes[bb + 3], lg = boxes[bb + 4];
        float rg = boxes[bb + 6];
        float ct = cosf(rg), st = sinf(rg);
        const float lxv[4] = {-0.5f, -0.16666667f, 0.16666667f, 0.5f};
        const float lyv[7] = {-0.5f, -0.33333334f, -0.16666667f, 0.f,
                               0.16666667f, 0.33333334f, 0.5f};
        int h = pl / 7, ww = pl - (pl / 7) * 7;
        float xx = lxv[h] * wg;
        float yy = lyv[ww] * lg;
        float gx = (xx * ct + yy * st + xg) * 2.5f;           // GRID_OFF.x = 0
        float gy = (yy * ct - xx * st + yg + 40.f) * 2.5f;    // GRID_OFF.y = 40
        float x0 = floorf(gx), y0 = floorf(gy);
        float fx = gx - x0, fy = gy - y0;
        int xi = (int)x0, yi = (int)y0;
        const float* base = feat2 + (long)b * HWDIM * PDIM + pl;
        float Ia = 0.f, Ib = 0.f, Ic = 0.f, Id = 0.f;
        if (yi >= 0 && yi < HDIM) {
            long r0 = (long)yi * WDIM;
            if (xi >= 0 && xi < WDIM)         Ia = base[(r0 + xi) * PDIM];
            if (xi + 1 >= 0 && xi + 1 < WDIM) Ic = base[(r0 + xi + 1) * PDIM];
        }
        if (yi + 1 >= 0 && yi + 1 < HDIM) {
            long r1 = (long)(yi + 1) * WDIM;
            if (xi >= 0 && xi < WDIM)         Ib = base[(r1 + xi) * PDIM];
            if (xi + 1 >= 0 && xi + 1 < WDIM) Id = base[(r1 + xi + 1) * PDIM];
        }
        val = (1.f - fx) * (1.f - fy) * Ia + (1.f - fx) * fy * Ib
            + fx * (1.f - fy) * Ic + fx * fy * Id;
    }
#pragma unroll
    for (int m = 16; m >= 1; m >>= 1) val += __shfl_xor(val, m, 64);
    if ((threadIdx.x & 31) == 0) {
        out[box] = val * (1.f / 28.f);
    }
}

// ---------- launch ----------
extern "C" void kernel_launch(void* const* d_in, const int* in_sizes, int n_in,
                              void* d_out, int out_size, void* d_ws, size_t ws_size,
                              hipStream_t stream) {
    const float* x     = (const float*)d_in[0];
    const float* boxes = (const float*)d_in[1];
    const float* w1    = (const float*)d_in[2];
    const float* g     = (const float*)d_in[3];
    const float* bt    = (const float*)d_in[4];
    const float* mn    = (const float*)d_in[5];
    const float* vr    = (const float*)d_in[6];
    const float* w2    = (const float*)d_in[7];
    float* out = (float*)d_out;

    char* ws = (char*)d_ws;
    unsigned short* xT2  = (unsigned short*)ws;                // 72,089,600 B
    float* feat2         = (float*)(ws + 72089600);            // 15,769,600 B
    unsigned short* BwT2 = (unsigned short*)(ws + 90112000);   //    147,456 B
    float* scale         = (float*)(ws + 90259456);            //        128 B
    float* shift         = (float*)(ws + 90259584);            //        128 B

    transpose_kernel<<<dim3(550, 4, 4), 256, 0, stream>>>(x, xT2);
    prep_kernel<<<289, 256, 0, stream>>>(w1, g, bt, mn, vr, BwT2, scale, shift);
    conv1_kernel<<<dim3(200, 4), 384, 0, stream>>>(xT2, BwT2, scale, shift, w2, feat2);
    sample_kernel<<<1024, 256, 0, stream>>>(boxes, feat2, out);
}

// Round 10
// 286.418 us; speedup vs baseline: 1.0530x; 1.0530x over previous
//
#include <hip/hip_runtime.h>
#include <hip/hip_bf16.h>

// PSWarpHead round 16. conv1: 64-px waves -- B shared across 2 M-tiles
// WITHIN one wave (no barriers, no LDS ring).
//   r15 post-mortem: B-via-LDS + 6-wave barriers = regression (99us, occ 14%,
//   2 blocks/CU). B-share is right but must be intra-wave. Fix: r12/r13's
//   registers-only barrier-free structure, wave = 64 px = two 32x32x16 tiles;
//   9 bq frags/step feed 18 MFMAs. Traffic 36->27 KB per 64px per step
//   (-25% on the binding TA/L1 path). Staged issue caps A liveness at 27
//   frags: [bq 9][aqn_t0 9] vmcnt(9) [MFMA t0] [aqn_t1 9] [MFMA t1].
//   cur=s&1 on a fully-unrolled loop (r12-proven parity; static indices).
//   2400 blocks, bijective XCD swizzle. Accumulation order per px identical
//   to r12 -> absmax 0.0009765625. transpose (r13) / prep / sample unchanged.

#define WDIM 176
#define HDIM 200
#define HWDIM 35200
#define CIN 256
#define PDIM 28
#define NBOX 2048

typedef __attribute__((ext_vector_type(8))) short bf16x8;
typedef __attribute__((ext_vector_type(4))) float floatx4;
typedef __attribute__((ext_vector_type(16))) float floatx16;

__device__ __forceinline__ unsigned short f2bf(float f) {
    unsigned int u; __builtin_memcpy(&u, &f, 4);
    unsigned int r = u + 0x7FFFu + ((u >> 16) & 1u);   // RNE
    return (unsigned short)(r >> 16);
}

// ---------- transpose: fp32 x [b][c][hw] -> bf16 xT2 [b][ksub][hw][16c] ----------
__global__ __launch_bounds__(256) void transpose_kernel(const float* __restrict__ x,
                                                        unsigned short* __restrict__ xT2) {
    __shared__ unsigned short st[64][72];
    int b = blockIdx.z, c0 = blockIdx.y * 64, px0 = blockIdx.x * 64;
    int t = threadIdx.x;

    int c_l = t >> 2, pq = t & 3;
    const float* sp = x + (long)(b * CIN + c0 + c_l) * HWDIM + px0 + pq * 16;
    float4 v0 = ((const float4*)sp)[0], v1 = ((const float4*)sp)[1];
    float4 v2 = ((const float4*)sp)[2], v3 = ((const float4*)sp)[3];
    int pr = pq * 16;
    st[pr +  0][c_l] = f2bf(v0.x); st[pr +  1][c_l] = f2bf(v0.y);
    st[pr +  2][c_l] = f2bf(v0.z); st[pr +  3][c_l] = f2bf(v0.w);
    st[pr +  4][c_l] = f2bf(v1.x); st[pr +  5][c_l] = f2bf(v1.y);
    st[pr +  6][c_l] = f2bf(v1.z); st[pr +  7][c_l] = f2bf(v1.w);
    st[pr +  8][c_l] = f2bf(v2.x); st[pr +  9][c_l] = f2bf(v2.y);
    st[pr + 10][c_l] = f2bf(v2.z); st[pr + 11][c_l] = f2bf(v2.w);
    st[pr + 12][c_l] = f2bf(v3.x); st[pr + 13][c_l] = f2bf(v3.y);
    st[pr + 14][c_l] = f2bf(v3.z); st[pr + 15][c_l] = f2bf(v3.w);
    __syncthreads();

    int w = t >> 6, l = t & 63;
    int ks = (c0 >> 4) + w;
    long pbase = ((long)(b * 16 + ks) * HWDIM + px0) * 16;
#pragma unroll
    for (int i = 0; i < 2; i++) {
        int px_l = i * 32 + (l >> 1);
        int hc = l & 1;
        bf16x8 frag = *(const bf16x8*)&st[px_l][w * 16 + hc * 8];
        *(bf16x8*)(xT2 + pbase + px_l * 16 + hc * 8) = frag;
    }
}

// ---------- prep: BwT2[f=tap*16+ks][lane=kh*32+n][8c] bf16; BN fold ----------
__global__ void prep_kernel(const float* __restrict__ w1,
                            const float* __restrict__ g, const float* __restrict__ bt,
                            const float* __restrict__ mn, const float* __restrict__ vr,
                            unsigned short* __restrict__ BwT2,
                            float* __restrict__ scale, float* __restrict__ shift) {
    int idx = blockIdx.x * 256 + threadIdx.x;
    if (idx < 9 * 16 * 64 * 8) {               // 73728
        int f = idx >> 9;
        int tap = f >> 4, ks = f & 15;
        int l = (idx >> 3) & 63;
        int e = idx & 7;
        int n = l & 31, kh = l >> 5;
        int c = ks * 16 + kh * 8 + e;
        BwT2[idx] = (n < PDIM) ? f2bf(w1[n * 2304 + c * 9 + tap]) : (unsigned short)0;
    } else if (idx < 73728 + 32) {
        int p = idx - 73728;
        if (p < PDIM) {
            float inv = g[p] / sqrtf(vr[p] + 1e-3f);
            scale[p] = inv;
            shift[p] = bt[p] - mn[p] * inv;
        } else { scale[p] = 0.f; shift[p] = 0.f; }
    }
}

// ---------- conv1: 1-wave 64-px blocks; registers-only; B shared by 2 tiles ----------
// block = (b, y, win): win in 0..2, px window [win*64, win*64+64).
// win2 tile1: px 160..191, lanes r32<16 valid (rest masked at write).
__global__ __launch_bounds__(64) void conv1_kernel(const unsigned short* __restrict__ xT2,
                                                   const unsigned short* __restrict__ BwT2,
                                                   const float* __restrict__ scale,
                                                   const float* __restrict__ shift,
                                                   const float* __restrict__ w2,
                                                   float* __restrict__ feat2) {
    __shared__ float t2f[32 * 36];             // epilogue tile (reused per M-tile)

    // XCD-chunked bijective swizzle over 2400 blocks (2400 % 8 == 0)
    int wg = blockIdx.y * 600 + blockIdx.x;
    int nl = (wg & 7) * 300 + (wg >> 3);
    int b = nl / 600;
    int rem = nl - b * 600;
    int y = rem / 3, win = rem - (rem / 3) * 3;
    int pxbase = win * 64;

    int lane = threadIdx.x;
    int r32 = lane & 31, khalf = lane >> 5;

    bool rowok[3];
#pragma unroll
    for (int rr = 0; rr < 3; rr++) rowok[rr] = (y + rr - 1 >= 0) && (y + rr - 1 < HDIM);
    // block-uniform per-tile edge flags: only win0 tile0 (px -1) and
    // win2 tile1 (px >= 176) have invalid x positions.
    bool edge0 = (win == 0), edge1 = (win == 2);

    bool xval[2][3];
    int  voff[2][3];
#pragma unroll
    for (int mt = 0; mt < 2; mt++) {
#pragma unroll
        for (int d = 0; d < 3; d++) {
            int xp = pxbase + mt * 32 + r32 + d - 1;
            xval[mt][d] = (xp >= 0) && (xp < WDIM);
            int xc = xp < 0 ? 0 : (xp > WDIM - 1 ? WDIM - 1 : xp);
            voff[mt][d] = xc * 32 + khalf * 16;
        }
    }

    const char* abase[3];
#pragma unroll
    for (int rr = 0; rr < 3; rr++) {
        int yc = y + rr - 1;
        yc = yc < 0 ? 0 : (yc > HDIM - 1 ? HDIM - 1 : yc);
        abase[rr] = (const char*)xT2 + ((long)b * 16 * HWDIM + (long)yc * WDIM) * 32;
    }
    const long KS = (long)HWDIM * 32;          // ksub plane stride (bytes)
    const char* bb = (const char*)BwT2 + lane * 16;

    // prologue: A fragments for step 0, both tiles (f = mt*9 + tap)
    bf16x8 aq[2][18];
#pragma unroll
    for (int f = 0; f < 18; f++)
        aq[0][f] = *(const bf16x8*)(abase[(f % 9) / 3] + voff[f / 9][f % 3]);

    floatx16 acc0 = {}, acc1 = {};

#pragma unroll
    for (int s = 0; s < 16; s++) {
        const int cur = s & 1, nxt = cur ^ 1;
        // B fragments for step s (9 loads, shared by both tiles)
        bf16x8 bq[9];
#pragma unroll
        for (int t = 0; t < 9; t++)
            bq[t] = *(const bf16x8*)(bb + t * 16384 + s * 1024);
        // A(s+1) tile0 (9 loads) -- liveness-staged: tile1's issued after t0 MFMAs
        if (s < 15) {
#pragma unroll
            for (int t = 0; t < 9; t++)
                aq[nxt][t] = *(const bf16x8*)(abase[t / 3] + KS * (s + 1) + voff[0][t % 3]);
            __builtin_amdgcn_sched_barrier(0);
            // outstanding: [aq(s) 18][bq 9][aqn_t0 9] -> keep 9 => aq(s)+bq done
            asm volatile("s_waitcnt vmcnt(9)" ::: "memory");
        } else {
            __builtin_amdgcn_sched_barrier(0);
            asm volatile("s_waitcnt vmcnt(0)" ::: "memory");
        }
        __builtin_amdgcn_sched_barrier(0);

        // ---- tile 0 MFMAs ----
        if (!edge0) {
#pragma unroll
            for (int t = 0; t < 9; t++) {
                if (!rowok[t / 3]) continue;   // block-uniform
                acc0 = __builtin_amdgcn_mfma_f32_32x32x16_bf16(aq[cur][t], bq[t], acc0, 0, 0, 0);
            }
        } else {
#pragma unroll
            for (int t = 0; t < 9; t++) {
                if (!rowok[t / 3]) continue;
                bf16x8 af = aq[cur][t];
                if (!xval[0][t % 3]) af = (bf16x8)0;
                acc0 = __builtin_amdgcn_mfma_f32_32x32x16_bf16(af, bq[t], acc0, 0, 0, 0);
            }
        }

        // A(s+1) tile1 (9 loads; stays in flight through tile1 MFMAs)
        if (s < 15) {
#pragma unroll
            for (int t = 0; t < 9; t++)
                aq[nxt][9 + t] = *(const bf16x8*)(abase[t / 3] + KS * (s + 1) + voff[1][t % 3]);
        }
        __builtin_amdgcn_sched_barrier(0);

        // ---- tile 1 MFMAs (operands aq(s)t1 + bq already retired) ----
        if (!edge1) {
#pragma unroll
            for (int t = 0; t < 9; t++) {
                if (!rowok[t / 3]) continue;
                acc1 = __builtin_amdgcn_mfma_f32_32x32x16_bf16(aq[cur][9 + t], bq[t], acc1, 0, 0, 0);
            }
        } else {
#pragma unroll
            for (int t = 0; t < 9; t++) {
                if (!rowok[t / 3]) continue;
                bf16x8 af = aq[cur][9 + t];
                if (!xval[1][t % 3]) af = (bf16x8)0;
                acc1 = __builtin_amdgcn_mfma_f32_32x32x16_bf16(af, bq[t], acc1, 0, 0, 0);
            }
        }
    }

    // ---- epilogue: BN + relu -> LDS tile -> fp32 conv2 matvec (per M-tile) ----
    // acc C/D (32x32): col n = lane&31, row px = (reg&3)+8*(reg>>2)+4*(lane>>5)
    long rowpix = (long)b * HWDIM + (long)y * WDIM;
    int n_l = r32;                 // output channel (<28 valid)
    float4 w2r[7];
#pragma unroll
    for (int jj = 0; jj < 7; jj++) {
        if (n_l < PDIM) w2r[jj] = ((const float4*)(w2 + n_l * PDIM))[jj];
        else            w2r[jj] = make_float4(0.f, 0.f, 0.f, 0.f);
    }
    float sc = scale[r32], sh2 = shift[r32];

#pragma unroll
    for (int mt = 0; mt < 2; mt++) {
        const floatx16& acc = mt ? acc1 : acc0;
#pragma unroll
        for (int i = 0; i < 16; i++) {
            int prow = (i & 3) + 8 * (i >> 2) + 4 * khalf;
            float v = fmaf(acc[i], sc, sh2);
            t2f[prow * 36 + r32] = v > 0.f ? v : 0.f;
        }
        // wave-internal LDS dependency: compiler inserts lgkmcnt waits.
#pragma unroll
        for (int i = 0; i < 16; i++) {
            int pxl = khalf * 16 + i;
            float s = 0.f;
#pragma unroll
            for (int jj = 0; jj < 7; jj++) {
                float4 a = *(const float4*)&t2f[pxl * 36 + jj * 4];
                s = fmaf(a.x, w2r[jj].x, s); s = fmaf(a.y, w2r[jj].y, s);
                s = fmaf(a.z, w2r[jj].z, s); s = fmaf(a.w, w2r[jj].w, s);
            }
            int px = pxbase + mt * 32 + pxl;
            if (n_l < PDIM && px < WDIM) feat2[(rowpix + px) * PDIM + n_l] = s;
        }
    }
}

// ---------- PS bilinear sampler on precomputed conv2 output (scalar gather) ----------
__global__ __launch_bounds__(256) void sample_kernel(const float* __restrict__ boxes,
                                                     const float* __restrict__ feat2,
                                                     float* __restrict__ out) {
    int gid = blockIdx.x * 256 + threadIdx.x;
    int box = gid >> 5;              // 32 lanes per box
    int pl = gid & 31;
    int b = box >> 11;
    float val = 0.f;
    if (pl < PDIM) {
        long bb = (long)box * 7;
        float xg = boxes[bb + 0], yg = boxes[bb + 1];
        float wg = boxes[bb + 3], lg = boxes[bb + 4];
        float rg = boxes[bb + 6];
        float ct = cosf(rg), st = sinf(rg);
        const float lxv[4] = {-0.5f, -0.16666667f, 0.16666667f, 0.5f};
        const float lyv[7] = {-0.5f, -0.33333334f, -0.16666667f, 0.f,
                               0.16666667f, 0.33333334f, 0.5f};
        int h = pl / 7, ww = pl - (pl / 7) * 7;
        float xx = lxv[h] * wg;
        float yy = lyv[ww] * lg;
        float gx = (xx * ct + yy * st + xg) * 2.5f;           // GRID_OFF.x = 0
        float gy = (yy * ct - xx * st + yg + 40.f) * 2.5f;    // GRID_OFF.y = 40
        float x0 = floorf(gx), y0 = floorf(gy);
        float fx = gx - x0, fy = gy - y0;
        int xi = (int)x0, yi = (int)y0;
        const float* base = feat2 + (long)b * HWDIM * PDIM + pl;
        float Ia = 0.f, Ib = 0.f, Ic = 0.f, Id = 0.f;
        if (yi >= 0 && yi < HDIM) {
            long r0 = (long)yi * WDIM;
            if (xi >= 0 && xi < WDIM)         Ia = base[(r0 + xi) * PDIM];
            if (xi + 1 >= 0 && xi + 1 < WDIM) Ic = base[(r0 + xi + 1) * PDIM];
        }
        if (yi + 1 >= 0 && yi + 1 < HDIM) {
            long r1 = (long)(yi + 1) * WDIM;
            if (xi >= 0 && xi < WDIM)         Ib = base[(r1 + xi) * PDIM];
            if (xi + 1 >= 0 && xi + 1 < WDIM) Id = base[(r1 + xi + 1) * PDIM];
        }
        val = (1.f - fx) * (1.f - fy) * Ia + (1.f - fx) * fy * Ib
            + fx * (1.f - fy) * Ic + fx * fy * Id;
    }
#pragma unroll
    for (int m = 16; m >= 1; m >>= 1) val += __shfl_xor(val, m, 64);
    if ((threadIdx.x & 31) == 0) {
        out[box] = val * (1.f / 28.f);
    }
}

// ---------- launch ----------
extern "C" void kernel_launch(void* const* d_in, const int* in_sizes, int n_in,
                              void* d_out, int out_size, void* d_ws, size_t ws_size,
                              hipStream_t stream) {
    const float* x     = (const float*)d_in[0];
    const float* boxes = (const float*)d_in[1];
    const float* w1    = (const float*)d_in[2];
    const float* g     = (const float*)d_in[3];
    const float* bt    = (const float*)d_in[4];
    const float* mn    = (const float*)d_in[5];
    const float* vr    = (const float*)d_in[6];
    const float* w2    = (const float*)d_in[7];
    float* out = (float*)d_out;

    char* ws = (char*)d_ws;
    unsigned short* xT2  = (unsigned short*)ws;                // 72,089,600 B
    float* feat2         = (float*)(ws + 72089600);            // 15,769,600 B
    unsigned short* BwT2 = (unsigned short*)(ws + 90112000);   //    147,456 B
    float* scale         = (float*)(ws + 90259456);            //        128 B
    float* shift         = (float*)(ws + 90259584);            //        128 B

    transpose_kernel<<<dim3(550, 4, 4), 256, 0, stream>>>(x, xT2);
    prep_kernel<<<289, 256, 0, stream>>>(w1, g, bt, mn, vr, BwT2, scale, shift);
    conv1_kernel<<<dim3(600, 4), 64, 0, stream>>>(xT2, BwT2, scale, shift, w2, feat2);
    sample_kernel<<<1024, 256, 0, stream>>>(boxes, feat2, out);
}

// Round 11
// 285.610 us; speedup vs baseline: 1.0560x; 1.0028x over previous
//
#include <hip/hip_runtime.h>
#include <hip/hip_bf16.h>

// PSWarpHead round 17 = round 13 revert (best verified: 284.23 us).
//   r16 post-mortem: dual-tile conv1 regressed ~2us (VGPR 120 << needed 220:
//   allocator never materialized the intended 36-frag pipeline). Clean-run
//   accounting (remainder-invariant 236.8us, exact on r10/r11): clean conv1
//   r12/13 ~= 48us; rocprof's 99-103 for r15/16 = replay artifact (cache-cold
//   xT2 under serialized counter collection). Composition: 168us harness
//   fills (86% HBM peak) + 35us transpose (HBM floor) + 48 conv1 + 15 sample
//   + 3 prep + gaps ~= 284. Final artifact = best config:
//   transpose: 64px x 64c tile, 1KB-contiguous wave writes (r13)
//   conv1: registers-only 32x32x16 MFMA, single-tile, in-order-vmcnt
//          pipeline, fused BN/relu/conv2 epilogue (r12)
//   sample: 4-corner scalar gather (r7)

#define WDIM 176
#define HDIM 200
#define HWDIM 35200
#define CIN 256
#define PDIM 28
#define NBOX 2048

typedef __attribute__((ext_vector_type(8))) short bf16x8;
typedef __attribute__((ext_vector_type(4))) float floatx4;
typedef __attribute__((ext_vector_type(16))) float floatx16;

__device__ __forceinline__ unsigned short f2bf(float f) {
    unsigned int u; __builtin_memcpy(&u, &f, 4);
    unsigned int r = u + 0x7FFFu + ((u >> 16) & 1u);   // RNE
    return (unsigned short)(r >> 16);
}

// ---------- transpose: fp32 x [b][c][hw] -> bf16 xT2 [b][ksub][hw][16c] ----------
// 64px x 64c tile, 256 thr. Phase2 writes are 1KB-contiguous per wave-inst.
__global__ __launch_bounds__(256) void transpose_kernel(const float* __restrict__ x,
                                                        unsigned short* __restrict__ xT2) {
    __shared__ unsigned short st[64][72];      // [px][c], pad 72 (144B rows, 16B-aligned)
    int b = blockIdx.z, c0 = blockIdx.y * 64, px0 = blockIdx.x * 64;
    int t = threadIdx.x;

    // phase 1: thread reads 16 px of one channel (64B contiguous), converts
    int c_l = t >> 2, pq = t & 3;
    const float* sp = x + (long)(b * CIN + c0 + c_l) * HWDIM + px0 + pq * 16;
    float4 v0 = ((const float4*)sp)[0], v1 = ((const float4*)sp)[1];
    float4 v2 = ((const float4*)sp)[2], v3 = ((const float4*)sp)[3];
    int pr = pq * 16;
    st[pr +  0][c_l] = f2bf(v0.x); st[pr +  1][c_l] = f2bf(v0.y);
    st[pr +  2][c_l] = f2bf(v0.z); st[pr +  3][c_l] = f2bf(v0.w);
    st[pr +  4][c_l] = f2bf(v1.x); st[pr +  5][c_l] = f2bf(v1.y);
    st[pr +  6][c_l] = f2bf(v1.z); st[pr +  7][c_l] = f2bf(v1.w);
    st[pr +  8][c_l] = f2bf(v2.x); st[pr +  9][c_l] = f2bf(v2.y);
    st[pr + 10][c_l] = f2bf(v2.z); st[pr + 11][c_l] = f2bf(v2.w);
    st[pr + 12][c_l] = f2bf(v3.x); st[pr + 13][c_l] = f2bf(v3.y);
    st[pr + 14][c_l] = f2bf(v3.z); st[pr + 15][c_l] = f2bf(v3.w);
    __syncthreads();

    // phase 2: wave w -> ksub plane (c0/16 + w); lane l -> px i*32+(l>>1),
    // half-16c (l&1). Store addr = base + l*16 -> contiguous 1KB per inst.
    int w = t >> 6, l = t & 63;
    int ks = (c0 >> 4) + w;
    long pbase = ((long)(b * 16 + ks) * HWDIM + px0) * 16;
#pragma unroll
    for (int i = 0; i < 2; i++) {
        int px_l = i * 32 + (l >> 1);
        int hc = l & 1;
        bf16x8 frag = *(const bf16x8*)&st[px_l][w * 16 + hc * 8];
        *(bf16x8*)(xT2 + pbase + px_l * 16 + hc * 8) = frag;
    }
}

// ---------- prep: BwT2[f=tap*16+ks][lane=kh*32+n][8c] bf16; BN fold ----------
__global__ void prep_kernel(const float* __restrict__ w1,
                            const float* __restrict__ g, const float* __restrict__ bt,
                            const float* __restrict__ mn, const float* __restrict__ vr,
                            unsigned short* __restrict__ BwT2,
                            float* __restrict__ scale, float* __restrict__ shift) {
    int idx = blockIdx.x * 256 + threadIdx.x;
    if (idx < 9 * 16 * 64 * 8) {               // 73728
        int f = idx >> 9;                      // 512 elems per fragment
        int tap = f >> 4, ks = f & 15;
        int l = (idx >> 3) & 63;
        int e = idx & 7;
        int n = l & 31, kh = l >> 5;
        int c = ks * 16 + kh * 8 + e;
        BwT2[idx] = (n < PDIM) ? f2bf(w1[n * 2304 + c * 9 + tap]) : (unsigned short)0;
    } else if (idx < 73728 + 32) {
        int p = idx - 73728;
        if (p < PDIM) {
            float inv = g[p] / sqrtf(vr[p] + 1e-3f);
            scale[p] = inv;
            shift[p] = bt[p] - mn[p] * inv;
        } else { scale[p] = 0.f; shift[p] = 0.f; }
    }
}

// ---------- conv1: registers-only 32x32x16 MFMA pipeline + fused epilogue ----------
// block = (b, y, win): 1 wave, window = 32 px (win5: 16 valid, rest masked).
__global__ __launch_bounds__(64) void conv1_kernel(const unsigned short* __restrict__ xT2,
                                                   const unsigned short* __restrict__ BwT2,
                                                   const float* __restrict__ scale,
                                                   const float* __restrict__ shift,
                                                   const float* __restrict__ w2,
                                                   float* __restrict__ feat2) {
    __shared__ float t2f[32 * 36];             // epilogue tile [32 px][36]

    // XCD-chunked bijective swizzle over 4800 blocks (4800 % 8 == 0)
    int wg = blockIdx.y * 1200 + blockIdx.x;
    int nl = (wg & 7) * 600 + (wg >> 3);
    int b = nl / 1200;
    int rem = nl - b * 1200;
    int y = rem / 6, win = rem - (rem / 6) * 6;
    int pxbase = win * 32;

    int lane = threadIdx.x;
    int r32 = lane & 31, khalf = lane >> 5;

    bool rowok[3];
#pragma unroll
    for (int rr = 0; rr < 3; rr++) rowok[rr] = (y + rr - 1 >= 0) && (y + rr - 1 < HDIM);
    bool edge = (win == 0) || (win == 5);      // only these have invalid px lanes

    // per-d lane validity + byte voffset into a ksub plane row
    bool xval[3];
    int  voff[3];
#pragma unroll
    for (int d = 0; d < 3; d++) {
        int xp = pxbase + r32 + d - 1;
        xval[d] = (xp >= 0) && (xp < WDIM);
        int xc = xp < 0 ? 0 : (xp > WDIM - 1 ? WDIM - 1 : xp);
        voff[d] = xc * 32 + khalf * 16;        // px*32B + khalf*16B
    }

    // block-uniform row bases (ks=0 plane), y-clamped; KS = ksub plane stride
    const char* abase[3];
#pragma unroll
    for (int rr = 0; rr < 3; rr++) {
        int yc = y + rr - 1;
        yc = yc < 0 ? 0 : (yc > HDIM - 1 ? HDIM - 1 : yc);
        abase[rr] = (const char*)xT2 + ((long)b * 16 * HWDIM + (long)yc * WDIM) * 32;
    }
    const long KS = (long)HWDIM * 32;          // 1,126,400 B per ksub plane
    const char* bb = (const char*)BwT2 + lane * 16;

    // prologue: A fragments for step 0
    bf16x8 aq[2][9];
#pragma unroll
    for (int t = 0; t < 9; t++)
        aq[0][t] = *(const bf16x8*)(abase[t / 3] + voff[t % 3]);

    floatx16 acc = {};

#pragma unroll
    for (int s = 0; s < 16; s++) {
        const int cur = s & 1, nxt = cur ^ 1;
        // B fragments for step s (issued BEFORE A-next: in-order vmcnt
        // retirement means waiting on these never drains A-next)
        bf16x8 bq[9];
#pragma unroll
        for (int t = 0; t < 9; t++)
            bq[t] = *(const bf16x8*)(bb + t * 16384 + s * 1024);
        if (s < 15) {
            // A fragments for step s+1 (9 loads, in flight through the MFMAs)
#pragma unroll
            for (int t = 0; t < 9; t++)
                aq[nxt][t] = *(const bf16x8*)(abase[t / 3] + KS * (s + 1) + voff[t % 3]);
            __builtin_amdgcn_sched_barrier(0);
            asm volatile("s_waitcnt vmcnt(18)" ::: "memory");   // A(s) done
        } else {
            __builtin_amdgcn_sched_barrier(0);
            asm volatile("s_waitcnt vmcnt(9)" ::: "memory");    // A(15) done
        }
        __builtin_amdgcn_sched_barrier(0);
        if (!edge) {
#pragma unroll
            for (int t = 0; t < 9; t++) {
                if (!rowok[t / 3]) continue;   // block-uniform
                acc = __builtin_amdgcn_mfma_f32_32x32x16_bf16(aq[cur][t], bq[t], acc, 0, 0, 0);
            }
        } else {
#pragma unroll
            for (int t = 0; t < 9; t++) {
                if (!rowok[t / 3]) continue;   // block-uniform
                bf16x8 af = aq[cur][t];
                if (!xval[t % 3]) af = (bf16x8)0;
                acc = __builtin_amdgcn_mfma_f32_32x32x16_bf16(af, bq[t], acc, 0, 0, 0);
            }
        }
    }

    // ---- epilogue: BN + relu -> LDS tile -> fp32 conv2 matvec ----
    // acc C/D (32x32): col n = lane&31, row px = (reg&3)+8*(reg>>2)+4*(lane>>5)
    {
        float sc = scale[r32], sh2 = shift[r32];
#pragma unroll
        for (int i = 0; i < 16; i++) {
            int prow = (i & 3) + 8 * (i >> 2) + 4 * khalf;
            float v = fmaf(acc[i], sc, sh2);
            t2f[prow * 36 + r32] = v > 0.f ? v : 0.f;
        }
    }
    long rowpix = (long)b * HWDIM + (long)y * WDIM;
    int n_l = r32;                 // output channel (<28 valid)
    float4 w2r[7];
#pragma unroll
    for (int jj = 0; jj < 7; jj++) {
        if (n_l < PDIM) w2r[jj] = ((const float4*)(w2 + n_l * PDIM))[jj];
        else            w2r[jj] = make_float4(0.f, 0.f, 0.f, 0.f);
    }
    // wave-internal LDS dependency: compiler inserts lgkmcnt waits.
#pragma unroll
    for (int i = 0; i < 16; i++) {
        int pxl = khalf * 16 + i;              // lanes 0-31: px 0-15; 32-63: 16-31
        float s = 0.f;
#pragma unroll
        for (int jj = 0; jj < 7; jj++) {
            float4 a = *(const float4*)&t2f[pxl * 36 + jj * 4];
            s = fmaf(a.x, w2r[jj].x, s); s = fmaf(a.y, w2r[jj].y, s);
            s = fmaf(a.z, w2r[jj].z, s); s = fmaf(a.w, w2r[jj].w, s);
        }
        int px = pxbase + pxl;
        if (n_l < PDIM && px < WDIM) feat2[(rowpix + px) * PDIM + n_l] = s;
    }
}

// ---------- PS bilinear sampler on precomputed conv2 output (scalar gather) ----------
__global__ __launch_bounds__(256) void sample_kernel(const float* __restrict__ boxes,
                                                     const float* __restrict__ feat2,
                                                     float* __restrict__ out) {
    int gid = blockIdx.x * 256 + threadIdx.x;
    int box = gid >> 5;              // 32 lanes per box
    int pl = gid & 31;
    int b = box >> 11;
    float val = 0.f;
    if (pl < PDIM) {
        long bb = (long)box * 7;
        float xg = boxes[bb + 0], yg = boxes[bb + 1];
        float wg = boxes[bb + 3], lg = boxes[bb + 4];
        float rg = boxes[bb + 6];
        float ct = cosf(rg), st = sinf(rg);
        const float lxv[4] = {-0.5f, -0.16666667f, 0.16666667f, 0.5f};
        const float lyv[7] = {-0.5f, -0.33333334f, -0.16666667f, 0.f,
                               0.16666667f, 0.33333334f, 0.5f};
        int h = pl / 7, ww = pl - (pl / 7) * 7;
        float xx = lxv[h] * wg;
        float yy = lyv[ww] * lg;
        float gx = (xx * ct + yy * st + xg) * 2.5f;           // GRID_OFF.x = 0
        float gy = (yy * ct - xx * st + yg + 40.f) * 2.5f;    // GRID_OFF.y = 40
        float x0 = floorf(gx), y0 = floorf(gy);
        float fx = gx - x0, fy = gy - y0;
        int xi = (int)x0, yi = (int)y0;
        const float* base = feat2 + (long)b * HWDIM * PDIM + pl;
        float Ia = 0.f, Ib = 0.f, Ic = 0.f, Id = 0.f;
        if (yi >= 0 && yi < HDIM) {
            long r0 = (long)yi * WDIM;
            if (xi >= 0 && xi < WDIM)         Ia = base[(r0 + xi) * PDIM];
            if (xi + 1 >= 0 && xi + 1 < WDIM) Ic = base[(r0 + xi + 1) * PDIM];
        }
        if (yi + 1 >= 0 && yi + 1 < HDIM) {
            long r1 = (long)(yi + 1) * WDIM;
            if (xi >= 0 && xi < WDIM)         Ib = base[(r1 + xi) * PDIM];
            if (xi + 1 >= 0 && xi + 1 < WDIM) Id = base[(r1 + xi + 1) * PDIM];
        }
        val = (1.f - fx) * (1.f - fy) * Ia + (1.f - fx) * fy * Ib
            + fx * (1.f - fy) * Ic + fx * fy * Id;
    }
#pragma unroll
    for (int m = 16; m >= 1; m >>= 1) val += __shfl_xor(val, m, 64);
    if ((threadIdx.x & 31) == 0) {
        out[box] = val * (1.f / 28.f);
    }
}

// ---------- launch ----------
extern "C" void kernel_launch(void* const* d_in, const int* in_sizes, int n_in,
                              void* d_out, int out_size, void* d_ws, size_t ws_size,
                              hipStream_t stream) {
    const float* x     = (const float*)d_in[0];
    const float* boxes = (const float*)d_in[1];
    const float* w1    = (const float*)d_in[2];
    const float* g     = (const float*)d_in[3];
    const float* bt    = (const float*)d_in[4];
    const float* mn    = (const float*)d_in[5];
    const float* vr    = (const float*)d_in[6];
    const float* w2    = (const float*)d_in[7];
    float* out = (float*)d_out;

    char* ws = (char*)d_ws;
    unsigned short* xT2  = (unsigned short*)ws;                // 72,089,600 B
    float* feat2         = (float*)(ws + 72089600);            // 15,769,600 B
    unsigned short* BwT2 = (unsigned short*)(ws + 90112000);   //    147,456 B
    float* scale         = (float*)(ws + 90259456);            //        128 B
    float* shift         = (float*)(ws + 90259584);            //        128 B

    transpose_kernel<<<dim3(550, 4, 4), 256, 0, stream>>>(x, xT2);
    prep_kernel<<<289, 256, 0, stream>>>(w1, g, bt, mn, vr, BwT2, scale, shift);
    conv1_kernel<<<dim3(1200, 4), 64, 0, stream>>>(xT2, BwT2, scale, shift, w2, feat2);
    sample_kernel<<<1024, 256, 0, stream>>>(boxes, feat2, out);
}